// Round 6
// baseline (764.901 us; speedup 1.0000x reference)
//
#include <hip/hip_runtime.h>

#define DIM 256
#define SCAN_B 256

typedef __attribute__((ext_vector_type(8))) short short8;
typedef __attribute__((ext_vector_type(4))) float f32x4;

__device__ __forceinline__ unsigned short f32_to_bf16(float x) {
    unsigned int u = __float_as_uint(x);
    unsigned int r = u + 0x7FFFu + ((u >> 16) & 1u);
    return (unsigned short)(r >> 16);
}
__device__ __forceinline__ float bf16_to_f32(unsigned short h) {
    return __uint_as_float(((unsigned int)h) << 16);
}

// ---------------- degree histogram ----------------
__global__ void deg_kernel(const int* __restrict__ dst, int E, int* __restrict__ deg) {
    int e = blockIdx.x * blockDim.x + threadIdx.x;
    if (e < E) atomicAdd(&deg[dst[e]], 1);
}

__global__ void invdeg_kernel(const int* __restrict__ deg, int N, float* __restrict__ inv_deg) {
    int n = blockIdx.x * blockDim.x + threadIdx.x;
    if (n < N) inv_deg[n] = 1.0f / (float)max(deg[n], 1);
}

// ---------------- hierarchical exclusive scan (deg -> row_start) ----------------
__global__ void scan1_kernel(const int* __restrict__ deg, int N,
                             int* __restrict__ excl, int* __restrict__ bsums) {
    __shared__ int s[SCAN_B];
    int tid = threadIdx.x;
    int i = blockIdx.x * SCAN_B + tid;
    int v = (i < N) ? deg[i] : 0;
    s[tid] = v;
    __syncthreads();
    #pragma unroll
    for (int off = 1; off < SCAN_B; off <<= 1) {
        int t = (tid >= off) ? s[tid - off] : 0;
        __syncthreads();
        s[tid] += t;
        __syncthreads();
    }
    if (i <= N) excl[i] = s[tid] - v;
    if (tid == SCAN_B - 1) bsums[blockIdx.x] = s[tid];
}

__global__ void scan2_kernel(int* __restrict__ bsums, int nb) {
    __shared__ int s[SCAN_B];
    int tid = threadIdx.x;
    int v = (tid < nb) ? bsums[tid] : 0;
    s[tid] = v;
    __syncthreads();
    #pragma unroll
    for (int off = 1; off < SCAN_B; off <<= 1) {
        int t = (tid >= off) ? s[tid - off] : 0;
        __syncthreads();
        s[tid] += t;
        __syncthreads();
    }
    if (tid < nb) bsums[tid] = s[tid] - v;
}

__global__ void scan3_kernel(const int* __restrict__ excl, const int* __restrict__ bsums,
                             int N, int* __restrict__ row_start) {
    int i = blockIdx.x * SCAN_B + threadIdx.x;
    if (i <= N) row_start[i] = excl[i] + bsums[blockIdx.x];
}

// ---------------- CSR bucket fill ----------------
__global__ void fill_kernel(const int* __restrict__ src, const int* __restrict__ dst, int E,
                            const int* __restrict__ row_start, int* __restrict__ cursor,
                            int* __restrict__ csr_src) {
    int e = blockIdx.x * blockDim.x + threadIdx.x;
    if (e < E) {
        int d = dst[e];
        int pos = row_start[d] + atomicAdd(&cursor[d], 1);
        csr_src[pos] = src[e];
    }
}

// ---------------- W -> transposed bf16 hi/lo split (R4-verified layout) ----------------
__global__ void wprep_kernel(const float* __restrict__ W,
                             unsigned short* __restrict__ Wt_hi,
                             unsigned short* __restrict__ Wt_lo) {
    int k = blockIdx.x;
    int n = threadIdx.x;
    float w = W[k * DIM + n];
    unsigned short hi = f32_to_bf16(w);
    float rem = w - bf16_to_f32(hi);
    Wt_hi[n * DIM + k] = hi;
    Wt_lo[n * DIM + k] = f32_to_bf16(rem);
}

// ---------------- x0 -> bf16 copy (layer-0 gather source) ----------------
__global__ void xprep_kernel(const float* __restrict__ x, unsigned short* __restrict__ xh, int n4) {
    int i = blockIdx.x * blockDim.x + threadIdx.x;
    if (i < n4) {
        float4 v = ((const float4*)x)[i];
        ushort4 o;
        o.x = f32_to_bf16(v.x); o.y = f32_to_bf16(v.y);
        o.z = f32_to_bf16(v.z); o.w = f32_to_bf16(v.w);
        ((ushort4*)xh)[i] = o;
    }
}

// ---------------- fused layer: gather+mix -> LDS (kb-plane layout) -> MFMA -> relu ----
// 64-node tile, 256 threads. LDS h layout: plane kb (0..7) holds [64 rows][32 k],
// i.e. element k of row r at As[(k>>5)*2048 + r*32 + (k&31)] — identical content
// to R4's per-kb staged As tiles, so fragment reads use the R4-verified formula.
template <bool LAST>
__global__ __launch_bounds__(256) void layer_kernel(
    const unsigned short* __restrict__ act_in, const float* __restrict__ x0,
    const int* __restrict__ row_start, const int* __restrict__ csr_src,
    const float* __restrict__ inv_deg,
    const unsigned short* __restrict__ Wt_hi, const unsigned short* __restrict__ Wt_lo,
    float* __restrict__ out_f32, unsigned short* __restrict__ out_bf16, int N)
{
    __shared__ unsigned short As_hi[8 * 64 * 32];  // 32 KB
    __shared__ unsigned short As_lo[8 * 64 * 32];  // 32 KB

    const int t    = threadIdx.x;
    const int w    = t >> 6;
    const int lane = t & 63;
    const int lm   = lane & 15;
    const int q    = lane >> 4;
    const int m0   = blockIdx.x * 64;
    const int c    = lane * 4;        // phase-1 column base
    const int ckb  = c >> 5;          // kb-plane of these 4 columns
    const int cko  = c & 31;          // offset within plane row

    // ---- phase 1: gather + residual mix, write bf16 hi/lo into LDS planes ----
    #pragma unroll 1
    for (int i = 0; i < 16; i++) {
        int r = i * 4 + w;            // wave-interleaved rows
        int node = m0 + r;
        if (node >= N) continue;
        int beg = row_start[node];
        int end = row_start[node + 1];

        float a0 = 0.f, a1 = 0.f, a2 = 0.f, a3 = 0.f;
        int e = beg;
        for (; e + 2 <= end; e += 2) {
            int s0 = csr_src[e];
            int s1 = csr_src[e + 1];
            ushort4 v0 = *(const ushort4*)(act_in + (size_t)s0 * DIM + c);
            ushort4 v1 = *(const ushort4*)(act_in + (size_t)s1 * DIM + c);
            a0 += bf16_to_f32(v0.x) + bf16_to_f32(v1.x);
            a1 += bf16_to_f32(v0.y) + bf16_to_f32(v1.y);
            a2 += bf16_to_f32(v0.z) + bf16_to_f32(v1.z);
            a3 += bf16_to_f32(v0.w) + bf16_to_f32(v1.w);
        }
        if (e < end) {
            int s0 = csr_src[e];
            ushort4 v0 = *(const ushort4*)(act_in + (size_t)s0 * DIM + c);
            a0 += bf16_to_f32(v0.x);
            a1 += bf16_to_f32(v0.y);
            a2 += bf16_to_f32(v0.z);
            a3 += bf16_to_f32(v0.w);
        }

        float scale = 0.9f * inv_deg[node];
        float4 xv = *(const float4*)(x0 + (size_t)node * DIM + c);
        float hv[4];
        hv[0] = 0.1f * xv.x + scale * a0;
        hv[1] = 0.1f * xv.y + scale * a1;
        hv[2] = 0.1f * xv.z + scale * a2;
        hv[3] = 0.1f * xv.w + scale * a3;

        ushort4 hi4, lo4;
        unsigned short* hp = &hi4.x;
        unsigned short* lp = &lo4.x;
        #pragma unroll
        for (int jj = 0; jj < 4; jj++) {
            unsigned short hb = f32_to_bf16(hv[jj]);
            hp[jj] = hb;
            lp[jj] = f32_to_bf16(hv[jj] - bf16_to_f32(hb));
        }
        int base = ckb * 2048 + r * 32 + cko;
        *(ushort4*)&As_hi[base] = hi4;
        *(ushort4*)&As_lo[base] = lo4;
    }
    __syncthreads();

    // ---- phase 2: barrier-free MFMA K-loop; B per-lane from global Wt (L2-hot) ----
    f32x4 acc[4][4];
    #pragma unroll
    for (int mi = 0; mi < 4; mi++)
        #pragma unroll
        for (int ni = 0; ni < 4; ni++)
            acc[mi][ni] = (f32x4){0.f, 0.f, 0.f, 0.f};

    #pragma unroll 1
    for (int kb = 0; kb < 8; kb++) {
        short8 b_hi[4], b_lo[4];
        #pragma unroll
        for (int ni = 0; ni < 4; ni++) {
            int n = w * 64 + ni * 16 + lm;                 // output column
            size_t off = (size_t)n * DIM + kb * 32 + q * 8;
            b_hi[ni] = *(const short8*)(Wt_hi + off);
            b_lo[ni] = *(const short8*)(Wt_lo + off);
        }
        short8 a_hi[4], a_lo[4];
        #pragma unroll
        for (int mi = 0; mi < 4; mi++) {
            int base = kb * 2048 + (mi * 16 + lm) * 32 + q * 8;   // R4 fragment formula
            a_hi[mi] = *(const short8*)&As_hi[base];
            a_lo[mi] = *(const short8*)&As_lo[base];
        }
        #pragma unroll
        for (int ni = 0; ni < 4; ni++) {
            #pragma unroll
            for (int mi = 0; mi < 4; mi++) {
                acc[mi][ni] = __builtin_amdgcn_mfma_f32_16x16x32_bf16(a_hi[mi], b_hi[ni], acc[mi][ni], 0, 0, 0);
                acc[mi][ni] = __builtin_amdgcn_mfma_f32_16x16x32_bf16(a_hi[mi], b_lo[ni], acc[mi][ni], 0, 0, 0);
                acc[mi][ni] = __builtin_amdgcn_mfma_f32_16x16x32_bf16(a_lo[mi], b_hi[ni], acc[mi][ni], 0, 0, 0);
            }
        }
    }

    // ---- epilogue: C/D layout col=lane&15, row=q*4+reg (R4-verified) ----
    #pragma unroll
    for (int mi = 0; mi < 4; mi++) {
        const int rowb = m0 + mi * 16 + q * 4;
        #pragma unroll
        for (int ni = 0; ni < 4; ni++) {
            const int col = w * 64 + ni * 16 + lm;
            #pragma unroll
            for (int r4 = 0; r4 < 4; r4++) {
                int row = rowb + r4;
                if (row < N) {
                    float v = fmaxf(acc[mi][ni][r4], 0.0f);
                    if (LAST) out_f32[(size_t)row * DIM + col] = v;
                    else      out_bf16[(size_t)row * DIM + col] = f32_to_bf16(v);
                }
            }
        }
    }
}

extern "C" void kernel_launch(void* const* d_in, const int* in_sizes, int n_in,
                              void* d_out, int out_size, void* d_ws, size_t ws_size,
                              hipStream_t stream) {
    const float* x0  = (const float*)d_in[0];
    const int*   ei  = (const int*)d_in[1];
    const float* W   = (const float*)d_in[2];
    float*       out = (float*)d_out;

    const int N = in_sizes[0] / DIM;
    const int E = in_sizes[1] / 2;
    const int N_pad = (N + 63) & ~63;
    const int* src = ei;
    const int* dst = ei + E;

    const int nb = (N + 1 + SCAN_B - 1) / SCAN_B;

    char* ws = (char*)d_ws;
    size_t off = 0;
    auto alloc = [&](size_t bytes) { char* p = ws + off; off += (bytes + 15) & ~size_t(15); return p; };
    unsigned short* act_a   = (unsigned short*)alloc((size_t)N_pad * DIM * 2);
    unsigned short* act_b   = (unsigned short*)alloc((size_t)N_pad * DIM * 2);
    unsigned short* Wt_hi   = (unsigned short*)alloc((size_t)DIM * DIM * 2);
    unsigned short* Wt_lo   = (unsigned short*)alloc((size_t)DIM * DIM * 2);
    float* inv_deg  = (float*)alloc((size_t)N * 4);
    int*   deg      = (int*)  alloc((size_t)N * 4);
    int*   row_start= (int*)  alloc((size_t)(N + 1) * 4);
    int*   excl     = (int*)  alloc((size_t)(N + 1) * 4);
    int*   cursor   = (int*)  alloc((size_t)N * 4);
    int*   bsums    = (int*)  alloc((size_t)nb * 4);
    int*   csr_src  = (int*)  alloc((size_t)E * 4);

    // ---- CSR build + W/x0 prep (per launch) ----
    hipMemsetAsync(deg, 0, (size_t)N * 4, stream);
    hipMemsetAsync(cursor, 0, (size_t)N * 4, stream);
    deg_kernel<<<(E + 255) / 256, 256, 0, stream>>>(dst, E, deg);
    invdeg_kernel<<<(N + 255) / 256, 256, 0, stream>>>(deg, N, inv_deg);
    scan1_kernel<<<nb, SCAN_B, 0, stream>>>(deg, N, excl, bsums);
    scan2_kernel<<<1, SCAN_B, 0, stream>>>(bsums, nb);
    scan3_kernel<<<nb, SCAN_B, 0, stream>>>(excl, bsums, N, row_start);
    fill_kernel<<<(E + 255) / 256, 256, 0, stream>>>(src, dst, E, row_start, cursor, csr_src);
    wprep_kernel<<<DIM, DIM, 0, stream>>>(W, Wt_hi, Wt_lo);
    const int n4 = N * DIM / 4;
    xprep_kernel<<<(n4 + 255) / 256, 256, 0, stream>>>(x0, act_a, n4);

    // ---- 5 fused GCN layers (activations ping-pong: a->b->a->b->a->out) ----
    const int grid = N_pad / 64;
    layer_kernel<false><<<grid, 256, 0, stream>>>(act_a, x0, row_start, csr_src, inv_deg,
                                                  Wt_hi, Wt_lo, nullptr, act_b, N);
    layer_kernel<false><<<grid, 256, 0, stream>>>(act_b, x0, row_start, csr_src, inv_deg,
                                                  Wt_hi, Wt_lo, nullptr, act_a, N);
    layer_kernel<false><<<grid, 256, 0, stream>>>(act_a, x0, row_start, csr_src, inv_deg,
                                                  Wt_hi, Wt_lo, nullptr, act_b, N);
    layer_kernel<false><<<grid, 256, 0, stream>>>(act_b, x0, row_start, csr_src, inv_deg,
                                                  Wt_hi, Wt_lo, nullptr, act_a, N);
    layer_kernel<true><<<grid, 256, 0, stream>>>(act_a, x0, row_start, csr_src, inv_deg,
                                                 Wt_hi, Wt_lo, out, nullptr, N);
}

// Round 7
// 646.851 us; speedup vs baseline: 1.1825x; 1.1825x over previous
//
#include <hip/hip_runtime.h>

#define DIM 256
#define SCAN_B 256

typedef __attribute__((ext_vector_type(8))) short short8;
typedef __attribute__((ext_vector_type(4))) float f32x4;

__device__ __forceinline__ unsigned short f32_to_bf16(float x) {
    unsigned int u = __float_as_uint(x);
    unsigned int r = u + 0x7FFFu + ((u >> 16) & 1u);
    return (unsigned short)(r >> 16);
}
__device__ __forceinline__ float bf16_to_f32(unsigned short h) {
    return __uint_as_float(((unsigned int)h) << 16);
}

// ---------------- degree histogram ----------------
__global__ void deg_kernel(const int* __restrict__ dst, int E, int* __restrict__ deg) {
    int e = blockIdx.x * blockDim.x + threadIdx.x;
    if (e < E) atomicAdd(&deg[dst[e]], 1);
}

__global__ void invdeg_kernel(const int* __restrict__ deg, int N, float* __restrict__ inv_deg) {
    int n = blockIdx.x * blockDim.x + threadIdx.x;
    if (n < N) inv_deg[n] = 1.0f / (float)max(deg[n], 1);
}

// ---------------- hierarchical exclusive scan (deg -> row_start) ----------------
__global__ void scan1_kernel(const int* __restrict__ deg, int N,
                             int* __restrict__ excl, int* __restrict__ bsums) {
    __shared__ int s[SCAN_B];
    int tid = threadIdx.x;
    int i = blockIdx.x * SCAN_B + tid;
    int v = (i < N) ? deg[i] : 0;
    s[tid] = v;
    __syncthreads();
    #pragma unroll
    for (int off = 1; off < SCAN_B; off <<= 1) {
        int t = (tid >= off) ? s[tid - off] : 0;
        __syncthreads();
        s[tid] += t;
        __syncthreads();
    }
    if (i <= N) excl[i] = s[tid] - v;
    if (tid == SCAN_B - 1) bsums[blockIdx.x] = s[tid];
}

__global__ void scan2_kernel(int* __restrict__ bsums, int nb) {
    __shared__ int s[SCAN_B];
    int tid = threadIdx.x;
    int v = (tid < nb) ? bsums[tid] : 0;
    s[tid] = v;
    __syncthreads();
    #pragma unroll
    for (int off = 1; off < SCAN_B; off <<= 1) {
        int t = (tid >= off) ? s[tid - off] : 0;
        __syncthreads();
        s[tid] += t;
        __syncthreads();
    }
    if (tid < nb) bsums[tid] = s[tid] - v;
}

__global__ void scan3_kernel(const int* __restrict__ excl, const int* __restrict__ bsums,
                             int N, int* __restrict__ row_start) {
    int i = blockIdx.x * SCAN_B + threadIdx.x;
    if (i <= N) row_start[i] = excl[i] + bsums[blockIdx.x];
}

// ---------------- CSR bucket fill ----------------
__global__ void fill_kernel(const int* __restrict__ src, const int* __restrict__ dst, int E,
                            const int* __restrict__ row_start, int* __restrict__ cursor,
                            int* __restrict__ csr_src) {
    int e = blockIdx.x * blockDim.x + threadIdx.x;
    if (e < E) {
        int d = dst[e];
        int pos = row_start[d] + atomicAdd(&cursor[d], 1);
        csr_src[pos] = src[e];
    }
}

// ---------------- W -> transposed bf16 hi/lo split ----------------
__global__ void wprep_kernel(const float* __restrict__ W,
                             unsigned short* __restrict__ Wt_hi,
                             unsigned short* __restrict__ Wt_lo) {
    int k = blockIdx.x;
    int n = threadIdx.x;
    float w = W[k * DIM + n];
    unsigned short hi = f32_to_bf16(w);
    float rem = w - bf16_to_f32(hi);
    Wt_hi[n * DIM + k] = hi;
    Wt_lo[n * DIM + k] = f32_to_bf16(rem);
}

// ---------------- x0 -> bf16 copy (layer-0 gather source) ----------------
__global__ void xprep_kernel(const float* __restrict__ x, unsigned short* __restrict__ xh, int n4) {
    int i = blockIdx.x * blockDim.x + threadIdx.x;
    if (i < n4) {
        float4 v = ((const float4*)x)[i];
        ushort4 o;
        o.x = f32_to_bf16(v.x); o.y = f32_to_bf16(v.y);
        o.z = f32_to_bf16(v.z); o.w = f32_to_bf16(v.w);
        ((ushort4*)xh)[i] = o;
    }
}

// ---------------- gather aggregation (bf16 src) + residual mix -> bf16 hi/lo h ----------------
// one 64-lane wave per node; lane owns 4 contiguous columns (8B loads). (R4-verified)
__global__ __launch_bounds__(256) void aggregate_kernel(
    const unsigned short* __restrict__ xh, const float* __restrict__ x0,
    const int* __restrict__ row_start, const int* __restrict__ csr_src,
    const float* __restrict__ inv_deg,
    unsigned short* __restrict__ h_hi, unsigned short* __restrict__ h_lo, int N)
{
    int node = blockIdx.x * 4 + (threadIdx.x >> 6);
    if (node >= N) return;
    int c = (threadIdx.x & 63) * 4;

    int beg = row_start[node];
    int end = row_start[node + 1];

    float a0 = 0.f, a1 = 0.f, a2 = 0.f, a3 = 0.f;
    int e = beg;
    for (; e + 2 <= end; e += 2) {
        int s0 = csr_src[e];
        int s1 = csr_src[e + 1];
        ushort4 v0 = *(const ushort4*)(xh + (size_t)s0 * DIM + c);
        ushort4 v1 = *(const ushort4*)(xh + (size_t)s1 * DIM + c);
        a0 += bf16_to_f32(v0.x) + bf16_to_f32(v1.x);
        a1 += bf16_to_f32(v0.y) + bf16_to_f32(v1.y);
        a2 += bf16_to_f32(v0.z) + bf16_to_f32(v1.z);
        a3 += bf16_to_f32(v0.w) + bf16_to_f32(v1.w);
    }
    if (e < end) {
        int s0 = csr_src[e];
        ushort4 v0 = *(const ushort4*)(xh + (size_t)s0 * DIM + c);
        a0 += bf16_to_f32(v0.x);
        a1 += bf16_to_f32(v0.y);
        a2 += bf16_to_f32(v0.z);
        a3 += bf16_to_f32(v0.w);
    }

    float scale = 0.9f * inv_deg[node];
    float4 xv = *(const float4*)(x0 + (size_t)node * DIM + c);
    float hv[4];
    hv[0] = 0.1f * xv.x + scale * a0;
    hv[1] = 0.1f * xv.y + scale * a1;
    hv[2] = 0.1f * xv.z + scale * a2;
    hv[3] = 0.1f * xv.w + scale * a3;

    ushort4 hi4, lo4;
    unsigned short* hp = &hi4.x;
    unsigned short* lp = &lo4.x;
    #pragma unroll
    for (int i = 0; i < 4; i++) {
        unsigned short hb = f32_to_bf16(hv[i]);
        hp[i] = hb;
        lp[i] = f32_to_bf16(hv[i] - bf16_to_f32(hb));
    }
    *(ushort4*)(h_hi + (size_t)node * DIM + c) = hi4;
    *(ushort4*)(h_lo + (size_t)node * DIM + c) = lo4;
}

// ---------------- no-LDS MFMA GEMM: out = relu(h @ W), bf16x3 ----------------
// 128x128 tile per block, 4 waves 2x2, each wave 4x4 frags of 16x16x32.
// A and B fragments read directly from global (both L2/L3-hot); no LDS, no barriers.
template <bool LAST>
__global__ __launch_bounds__(256) void gemm_kernel(
    const unsigned short* __restrict__ h_hi, const unsigned short* __restrict__ h_lo,
    const unsigned short* __restrict__ Wt_hi, const unsigned short* __restrict__ Wt_lo,
    float* __restrict__ out_f32, unsigned short* __restrict__ out_bf16, int N)
{
    const int t    = threadIdx.x;
    const int w    = t >> 6;
    const int lane = t & 63;
    const int lm   = lane & 15;
    const int q    = lane >> 4;
    const int wm   = w >> 1, wn = w & 1;
    const int m0   = blockIdx.x * 128;
    const int n0   = blockIdx.y * 128;

    f32x4 acc[4][4];
    #pragma unroll
    for (int mi = 0; mi < 4; mi++)
        #pragma unroll
        for (int ni = 0; ni < 4; ni++)
            acc[mi][ni] = (f32x4){0.f, 0.f, 0.f, 0.f};

    const size_t abase = (size_t)(m0 + wm * 64 + lm) * DIM + q * 8;
    const size_t bbase = (size_t)(n0 + wn * 64 + lm) * DIM + q * 8;

    #pragma unroll 1
    for (int kb = 0; kb < 8; kb++) {
        short8 a_hi[4], a_lo[4], b_hi[4], b_lo[4];
        #pragma unroll
        for (int i = 0; i < 4; i++) {
            size_t aoff = abase + (size_t)i * 16 * DIM + kb * 32;
            a_hi[i] = *(const short8*)(h_hi + aoff);
            a_lo[i] = *(const short8*)(h_lo + aoff);
            size_t boff = bbase + (size_t)i * 16 * DIM + kb * 32;
            b_hi[i] = *(const short8*)(Wt_hi + boff);
            b_lo[i] = *(const short8*)(Wt_lo + boff);
        }
        #pragma unroll
        for (int ni = 0; ni < 4; ni++) {
            #pragma unroll
            for (int mi = 0; mi < 4; mi++) {
                acc[mi][ni] = __builtin_amdgcn_mfma_f32_16x16x32_bf16(a_hi[mi], b_hi[ni], acc[mi][ni], 0, 0, 0);
                acc[mi][ni] = __builtin_amdgcn_mfma_f32_16x16x32_bf16(a_hi[mi], b_lo[ni], acc[mi][ni], 0, 0, 0);
                acc[mi][ni] = __builtin_amdgcn_mfma_f32_16x16x32_bf16(a_lo[mi], b_hi[ni], acc[mi][ni], 0, 0, 0);
            }
        }
    }

    // epilogue: C/D layout col=lane&15, row=q*4+reg (verified R4)
    #pragma unroll
    for (int mi = 0; mi < 4; mi++) {
        const int rowb = m0 + wm * 64 + mi * 16 + q * 4;
        #pragma unroll
        for (int ni = 0; ni < 4; ni++) {
            const int col = n0 + wn * 64 + ni * 16 + lm;
            #pragma unroll
            for (int r = 0; r < 4; r++) {
                int row = rowb + r;
                if (row < N) {
                    float v = fmaxf(acc[mi][ni][r], 0.0f);
                    if (LAST) out_f32[(size_t)row * DIM + col] = v;
                    else      out_bf16[(size_t)row * DIM + col] = f32_to_bf16(v);
                }
            }
        }
    }
}

extern "C" void kernel_launch(void* const* d_in, const int* in_sizes, int n_in,
                              void* d_out, int out_size, void* d_ws, size_t ws_size,
                              hipStream_t stream) {
    const float* x0  = (const float*)d_in[0];
    const int*   ei  = (const int*)d_in[1];
    const float* W   = (const float*)d_in[2];
    float*       out = (float*)d_out;

    const int N = in_sizes[0] / DIM;
    const int E = in_sizes[1] / 2;
    const int N_pad = (N + 127) & ~127;
    const int* src = ei;
    const int* dst = ei + E;

    const int nb = (N + 1 + SCAN_B - 1) / SCAN_B;

    char* ws = (char*)d_ws;
    size_t off = 0;
    auto alloc = [&](size_t bytes) { char* p = ws + off; off += (bytes + 15) & ~size_t(15); return p; };
    unsigned short* h_hi    = (unsigned short*)alloc((size_t)N_pad * DIM * 2);
    unsigned short* h_lo    = (unsigned short*)alloc((size_t)N_pad * DIM * 2);
    unsigned short* act     = (unsigned short*)alloc((size_t)N_pad * DIM * 2);
    unsigned short* Wt_hi   = (unsigned short*)alloc((size_t)DIM * DIM * 2);
    unsigned short* Wt_lo   = (unsigned short*)alloc((size_t)DIM * DIM * 2);
    float* inv_deg  = (float*)alloc((size_t)N * 4);
    int*   deg      = (int*)  alloc((size_t)N * 4);
    int*   row_start= (int*)  alloc((size_t)(N + 1) * 4);
    int*   excl     = (int*)  alloc((size_t)(N + 1) * 4);
    int*   cursor   = (int*)  alloc((size_t)N * 4);
    int*   bsums    = (int*)  alloc((size_t)nb * 4);
    int*   csr_src  = (int*)  alloc((size_t)E * 4);

    // ---- CSR build + W/x0 prep (per launch) ----
    hipMemsetAsync(deg, 0, (size_t)N * 4, stream);
    hipMemsetAsync(cursor, 0, (size_t)N * 4, stream);
    deg_kernel<<<(E + 255) / 256, 256, 0, stream>>>(dst, E, deg);
    invdeg_kernel<<<(N + 255) / 256, 256, 0, stream>>>(deg, N, inv_deg);
    scan1_kernel<<<nb, SCAN_B, 0, stream>>>(deg, N, excl, bsums);
    scan2_kernel<<<1, SCAN_B, 0, stream>>>(bsums, nb);
    scan3_kernel<<<nb, SCAN_B, 0, stream>>>(excl, bsums, N, row_start);
    fill_kernel<<<(E + 255) / 256, 256, 0, stream>>>(src, dst, E, row_start, cursor, csr_src);
    wprep_kernel<<<DIM, DIM, 0, stream>>>(W, Wt_hi, Wt_lo);
    const int n4 = N * DIM / 4;
    xprep_kernel<<<(n4 + 255) / 256, 256, 0, stream>>>(x0, act, n4);

    // ---- 5 GCN layers ----
    dim3 ggrid(N_pad / 128, 2);
    for (int layer = 0; layer < 5; layer++) {
        aggregate_kernel<<<(N + 3) / 4, 256, 0, stream>>>(act, x0, row_start, csr_src,
                                                          inv_deg, h_hi, h_lo, N);
        if (layer == 4)
            gemm_kernel<true><<<ggrid, 256, 0, stream>>>(h_hi, h_lo, Wt_hi, Wt_lo, out, nullptr, N);
        else
            gemm_kernel<false><<<ggrid, 256, 0, stream>>>(h_hi, h_lo, Wt_hi, Wt_lo, nullptr, act, N);
    }
}

// Round 8
// 442.855 us; speedup vs baseline: 1.7272x; 1.4606x over previous
//
#include <hip/hip_runtime.h>

#define DIM 256
#define SCAN_B 256

typedef __attribute__((ext_vector_type(8))) short short8;
typedef __attribute__((ext_vector_type(4))) float f32x4;

__device__ __forceinline__ unsigned short f32_to_bf16(float x) {
    unsigned int u = __float_as_uint(x);
    unsigned int r = u + 0x7FFFu + ((u >> 16) & 1u);
    return (unsigned short)(r >> 16);
}
__device__ __forceinline__ float bf16_to_f32(unsigned short h) {
    return __uint_as_float(((unsigned int)h) << 16);
}

__device__ __forceinline__ void load_lds16(const void* g, void* l) {
    __builtin_amdgcn_global_load_lds(
        (const __attribute__((address_space(1))) unsigned int*)g,
        (__attribute__((address_space(3))) unsigned int*)l, 16, 0, 0);
}

// ---------------- degree histogram ----------------
__global__ void deg_kernel(const int* __restrict__ dst, int E, int* __restrict__ deg) {
    int e = blockIdx.x * blockDim.x + threadIdx.x;
    if (e < E) atomicAdd(&deg[dst[e]], 1);
}

__global__ void invdeg_kernel(const int* __restrict__ deg, int N, float* __restrict__ inv_deg) {
    int n = blockIdx.x * blockDim.x + threadIdx.x;
    if (n < N) inv_deg[n] = 1.0f / (float)max(deg[n], 1);
}

// ---------------- hierarchical exclusive scan (deg -> row_start) ----------------
__global__ void scan1_kernel(const int* __restrict__ deg, int N,
                             int* __restrict__ excl, int* __restrict__ bsums) {
    __shared__ int s[SCAN_B];
    int tid = threadIdx.x;
    int i = blockIdx.x * SCAN_B + tid;
    int v = (i < N) ? deg[i] : 0;
    s[tid] = v;
    __syncthreads();
    #pragma unroll
    for (int off = 1; off < SCAN_B; off <<= 1) {
        int t = (tid >= off) ? s[tid - off] : 0;
        __syncthreads();
        s[tid] += t;
        __syncthreads();
    }
    if (i <= N) excl[i] = s[tid] - v;
    if (tid == SCAN_B - 1) bsums[blockIdx.x] = s[tid];
}

__global__ void scan2_kernel(int* __restrict__ bsums, int nb) {
    __shared__ int s[SCAN_B];
    int tid = threadIdx.x;
    int v = (tid < nb) ? bsums[tid] : 0;
    s[tid] = v;
    __syncthreads();
    #pragma unroll
    for (int off = 1; off < SCAN_B; off <<= 1) {
        int t = (tid >= off) ? s[tid - off] : 0;
        __syncthreads();
        s[tid] += t;
        __syncthreads();
    }
    if (tid < nb) bsums[tid] = s[tid] - v;
}

__global__ void scan3_kernel(const int* __restrict__ excl, const int* __restrict__ bsums,
                             int N, int* __restrict__ row_start) {
    int i = blockIdx.x * SCAN_B + threadIdx.x;
    if (i <= N) row_start[i] = excl[i] + bsums[blockIdx.x];
}

// ---------------- CSR bucket fill ----------------
__global__ void fill_kernel(const int* __restrict__ src, const int* __restrict__ dst, int E,
                            const int* __restrict__ row_start, int* __restrict__ cursor,
                            int* __restrict__ csr_src) {
    int e = blockIdx.x * blockDim.x + threadIdx.x;
    if (e < E) {
        int d = dst[e];
        int pos = row_start[d] + atomicAdd(&cursor[d], 1);
        csr_src[pos] = src[e];
    }
}

// ---------------- W -> transposed bf16 hi/lo split ----------------
__global__ void wprep_kernel(const float* __restrict__ W,
                             unsigned short* __restrict__ Wt_hi,
                             unsigned short* __restrict__ Wt_lo) {
    int k = blockIdx.x;
    int n = threadIdx.x;
    float w = W[k * DIM + n];
    unsigned short hi = f32_to_bf16(w);
    float rem = w - bf16_to_f32(hi);
    Wt_hi[n * DIM + k] = hi;
    Wt_lo[n * DIM + k] = f32_to_bf16(rem);
}

// ---------------- x0 -> bf16 (layer-0 gather source AND residual source) ----------------
__global__ void xprep_kernel(const float* __restrict__ x, unsigned short* __restrict__ act,
                             unsigned short* __restrict__ x0b, int n4) {
    int i = blockIdx.x * blockDim.x + threadIdx.x;
    if (i < n4) {
        float4 v = ((const float4*)x)[i];
        ushort4 o;
        o.x = f32_to_bf16(v.x); o.y = f32_to_bf16(v.y);
        o.z = f32_to_bf16(v.z); o.w = f32_to_bf16(v.w);
        ((ushort4*)act)[i] = o;
        ((ushort4*)x0b)[i] = o;
    }
}

// ---------------- gather aggregation (bf16 src) + residual mix -> bf16 h ----------------
// one 64-lane wave per node; lane owns 4 contiguous columns (8B loads).
__global__ __launch_bounds__(256) void aggregate_kernel(
    const unsigned short* __restrict__ xh, const unsigned short* __restrict__ x0b,
    const int* __restrict__ row_start, const int* __restrict__ csr_src,
    const float* __restrict__ inv_deg,
    unsigned short* __restrict__ h, int N)
{
    int node = blockIdx.x * 4 + (threadIdx.x >> 6);
    if (node >= N) return;
    int c = (threadIdx.x & 63) * 4;

    int beg = row_start[node];
    int end = row_start[node + 1];

    float a0 = 0.f, a1 = 0.f, a2 = 0.f, a3 = 0.f;
    int e = beg;
    for (; e + 2 <= end; e += 2) {
        int s0 = csr_src[e];
        int s1 = csr_src[e + 1];
        ushort4 v0 = *(const ushort4*)(xh + (size_t)s0 * DIM + c);
        ushort4 v1 = *(const ushort4*)(xh + (size_t)s1 * DIM + c);
        a0 += bf16_to_f32(v0.x) + bf16_to_f32(v1.x);
        a1 += bf16_to_f32(v0.y) + bf16_to_f32(v1.y);
        a2 += bf16_to_f32(v0.z) + bf16_to_f32(v1.z);
        a3 += bf16_to_f32(v0.w) + bf16_to_f32(v1.w);
    }
    if (e < end) {
        int s0 = csr_src[e];
        ushort4 v0 = *(const ushort4*)(xh + (size_t)s0 * DIM + c);
        a0 += bf16_to_f32(v0.x);
        a1 += bf16_to_f32(v0.y);
        a2 += bf16_to_f32(v0.z);
        a3 += bf16_to_f32(v0.w);
    }

    float scale = 0.9f * inv_deg[node];
    ushort4 xv = *(const ushort4*)(x0b + (size_t)node * DIM + c);
    ushort4 o;
    o.x = f32_to_bf16(0.1f * bf16_to_f32(xv.x) + scale * a0);
    o.y = f32_to_bf16(0.1f * bf16_to_f32(xv.y) + scale * a1);
    o.z = f32_to_bf16(0.1f * bf16_to_f32(xv.z) + scale * a2);
    o.w = f32_to_bf16(0.1f * bf16_to_f32(xv.w) + scale * a3);
    *(ushort4*)(h + (size_t)node * DIM + c) = o;
}

// ---------------- LDS-staged MFMA GEMM: out = relu(h @ W), A bf16 / W bf16x2 ----------------
// 128x128 tile per 256-thread block; 4 waves 2x2; each wave 4x4 frags of 16x16x32.
template <bool LAST>
__global__ __launch_bounds__(256) void gemm_kernel(
    const unsigned short* __restrict__ h,
    const unsigned short* __restrict__ Wt_hi, const unsigned short* __restrict__ Wt_lo,
    float* __restrict__ out_f32, unsigned short* __restrict__ out_bf16, int N)
{
    __shared__ unsigned short As[128 * 32];     // 8 KB
    __shared__ unsigned short Bs_hi[128 * 32];  // 8 KB
    __shared__ unsigned short Bs_lo[128 * 32];  // 8 KB

    const int t    = threadIdx.x;
    const int w    = t >> 6;
    const int lane = t & 63;
    const int lm   = lane & 15;
    const int q    = lane >> 4;
    const int wm   = w >> 1, wn = w & 1;
    const int m0   = blockIdx.x * 128;
    const int n0   = blockIdx.y * 128;

    // staging: thread t loads 6 x 16B granules; rows r = half*64 + t>>2, granule g = t&3
    const int sr = t >> 2;     // 0..63
    const int sg = (t & 3) * 8;

    f32x4 acc[4][4];
    #pragma unroll
    for (int mi = 0; mi < 4; mi++)
        #pragma unroll
        for (int ni = 0; ni < 4; ni++)
            acc[mi][ni] = (f32x4){0.f, 0.f, 0.f, 0.f};

    for (int kb = 0; kb < DIM; kb += 32) {
        __syncthreads();   // prior compute done before overwriting LDS
        #pragma unroll
        for (int half = 0; half < 2; half++) {
            int r = half * 64 + sr;
            int ldso = (half * 256 + t) * 8;
            load_lds16(h     + (size_t)(m0 + r) * DIM + kb + sg, &As[ldso]);
            load_lds16(Wt_hi + (size_t)(n0 + r) * DIM + kb + sg, &Bs_hi[ldso]);
            load_lds16(Wt_lo + (size_t)(n0 + r) * DIM + kb + sg, &Bs_lo[ldso]);
        }
        __syncthreads();   // drains vmcnt -> staged data visible

        short8 a[4];
        #pragma unroll
        for (int mi = 0; mi < 4; mi++) {
            int row = wm * 64 + mi * 16 + lm;
            a[mi] = *(const short8*)&As[row * 32 + q * 8];
        }
        #pragma unroll
        for (int ni = 0; ni < 4; ni++) {
            int row = wn * 64 + ni * 16 + lm;
            short8 b_hi = *(const short8*)&Bs_hi[row * 32 + q * 8];
            short8 b_lo = *(const short8*)&Bs_lo[row * 32 + q * 8];
            #pragma unroll
            for (int mi = 0; mi < 4; mi++) {
                acc[mi][ni] = __builtin_amdgcn_mfma_f32_16x16x32_bf16(a[mi], b_hi, acc[mi][ni], 0, 0, 0);
                acc[mi][ni] = __builtin_amdgcn_mfma_f32_16x16x32_bf16(a[mi], b_lo, acc[mi][ni], 0, 0, 0);
            }
        }
    }

    // epilogue: C/D layout col=lane&15, row=q*4+reg (verified R4)
    #pragma unroll
    for (int mi = 0; mi < 4; mi++) {
        const int rowb = m0 + wm * 64 + mi * 16 + q * 4;
        #pragma unroll
        for (int ni = 0; ni < 4; ni++) {
            const int col = n0 + wn * 64 + ni * 16 + lm;
            #pragma unroll
            for (int r = 0; r < 4; r++) {
                int row = rowb + r;
                if (row < N) {
                    float v = fmaxf(acc[mi][ni][r], 0.0f);
                    if (LAST) out_f32[(size_t)row * DIM + col] = v;
                    else      out_bf16[(size_t)row * DIM + col] = f32_to_bf16(v);
                }
            }
        }
    }
}

extern "C" void kernel_launch(void* const* d_in, const int* in_sizes, int n_in,
                              void* d_out, int out_size, void* d_ws, size_t ws_size,
                              hipStream_t stream) {
    const float* x0  = (const float*)d_in[0];
    const int*   ei  = (const int*)d_in[1];
    const float* W   = (const float*)d_in[2];
    float*       out = (float*)d_out;

    const int N = in_sizes[0] / DIM;
    const int E = in_sizes[1] / 2;
    const int N_pad = (N + 127) & ~127;
    const int* src = ei;
    const int* dst = ei + E;

    const int nb = (N + 1 + SCAN_B - 1) / SCAN_B;

    char* ws = (char*)d_ws;
    size_t off = 0;
    auto alloc = [&](size_t bytes) { char* p = ws + off; off += (bytes + 15) & ~size_t(15); return p; };
    unsigned short* h       = (unsigned short*)alloc((size_t)N_pad * DIM * 2);
    unsigned short* act     = (unsigned short*)alloc((size_t)N_pad * DIM * 2);
    unsigned short* x0b     = (unsigned short*)alloc((size_t)N_pad * DIM * 2);
    unsigned short* Wt_hi   = (unsigned short*)alloc((size_t)DIM * DIM * 2);
    unsigned short* Wt_lo   = (unsigned short*)alloc((size_t)DIM * DIM * 2);
    float* inv_deg  = (float*)alloc((size_t)N * 4);
    int*   deg      = (int*)  alloc((size_t)N * 4);
    int*   row_start= (int*)  alloc((size_t)(N + 1) * 4);
    int*   excl     = (int*)  alloc((size_t)(N + 1) * 4);
    int*   cursor   = (int*)  alloc((size_t)N * 4);
    int*   bsums    = (int*)  alloc((size_t)nb * 4);
    int*   csr_src  = (int*)  alloc((size_t)E * 4);

    // ---- CSR build + W/x0 prep (per launch) ----
    hipMemsetAsync(deg, 0, (size_t)N * 4, stream);
    hipMemsetAsync(cursor, 0, (size_t)N * 4, stream);
    deg_kernel<<<(E + 255) / 256, 256, 0, stream>>>(dst, E, deg);
    invdeg_kernel<<<(N + 255) / 256, 256, 0, stream>>>(deg, N, inv_deg);
    scan1_kernel<<<nb, SCAN_B, 0, stream>>>(deg, N, excl, bsums);
    scan2_kernel<<<1, SCAN_B, 0, stream>>>(bsums, nb);
    scan3_kernel<<<nb, SCAN_B, 0, stream>>>(excl, bsums, N, row_start);
    fill_kernel<<<(E + 255) / 256, 256, 0, stream>>>(src, dst, E, row_start, cursor, csr_src);
    wprep_kernel<<<DIM, DIM, 0, stream>>>(W, Wt_hi, Wt_lo);
    const int n4 = N * DIM / 4;
    xprep_kernel<<<(n4 + 255) / 256, 256, 0, stream>>>(x0, act, x0b, n4);

    // ---- 5 GCN layers ----
    dim3 ggrid(N_pad / 128, 2);
    for (int layer = 0; layer < 5; layer++) {
        aggregate_kernel<<<(N + 3) / 4, 256, 0, stream>>>(act, x0b, row_start, csr_src,
                                                          inv_deg, h, N);
        if (layer == 4)
            gemm_kernel<true><<<ggrid, 256, 0, stream>>>(h, Wt_hi, Wt_lo, out, nullptr, N);
        else
            gemm_kernel<false><<<ggrid, 256, 0, stream>>>(h, Wt_hi, Wt_lo, nullptr, act, N);
    }
}

// Round 9
// 395.960 us; speedup vs baseline: 1.9318x; 1.1184x over previous
//
#include <hip/hip_runtime.h>

#define DIM 256
#define SCAN_B 256

typedef __attribute__((ext_vector_type(8))) short short8;
typedef __attribute__((ext_vector_type(4))) float f32x4;

__device__ __forceinline__ unsigned short f32_to_bf16(float x) {
    unsigned int u = __float_as_uint(x);
    unsigned int r = u + 0x7FFFu + ((u >> 16) & 1u);
    return (unsigned short)(r >> 16);
}
__device__ __forceinline__ float bf16_to_f32(unsigned short h) {
    return __uint_as_float(((unsigned int)h) << 16);
}

__device__ __forceinline__ void load_lds16(const void* g, void* l) {
    __builtin_amdgcn_global_load_lds(
        (const __attribute__((address_space(1))) unsigned int*)g,
        (__attribute__((address_space(3))) unsigned int*)l, 16, 0, 0);
}

// ---------------- degree histogram ----------------
__global__ void deg_kernel(const int* __restrict__ dst, int E, int* __restrict__ deg) {
    int e = blockIdx.x * blockDim.x + threadIdx.x;
    if (e < E) atomicAdd(&deg[dst[e]], 1);
}

// ---------------- hierarchical exclusive scan (deg -> row_start) ----------------
__global__ void scan1_kernel(const int* __restrict__ deg, int N,
                             int* __restrict__ excl, int* __restrict__ bsums) {
    __shared__ int s[SCAN_B];
    int tid = threadIdx.x;
    int i = blockIdx.x * SCAN_B + tid;
    int v = (i < N) ? deg[i] : 0;
    s[tid] = v;
    __syncthreads();
    #pragma unroll
    for (int off = 1; off < SCAN_B; off <<= 1) {
        int t = (tid >= off) ? s[tid - off] : 0;
        __syncthreads();
        s[tid] += t;
        __syncthreads();
    }
    if (i <= N) excl[i] = s[tid] - v;
    if (tid == SCAN_B - 1) bsums[blockIdx.x] = s[tid];
}

__global__ void scan2_kernel(int* __restrict__ bsums, int nb) {
    __shared__ int s[SCAN_B];
    int tid = threadIdx.x;
    int v = (tid < nb) ? bsums[tid] : 0;
    s[tid] = v;
    __syncthreads();
    #pragma unroll
    for (int off = 1; off < SCAN_B; off <<= 1) {
        int t = (tid >= off) ? s[tid - off] : 0;
        __syncthreads();
        s[tid] += t;
        __syncthreads();
    }
    if (tid < nb) bsums[tid] = s[tid] - v;
}

// scan3 + inv_deg fused
__global__ void scan3_kernel(const int* __restrict__ excl, const int* __restrict__ bsums,
                             const int* __restrict__ deg, int N,
                             int* __restrict__ row_start, float* __restrict__ inv_deg) {
    int i = blockIdx.x * SCAN_B + threadIdx.x;
    if (i <= N) row_start[i] = excl[i] + bsums[blockIdx.x];
    if (i < N) inv_deg[i] = 1.0f / (float)max(deg[i], 1);
}

// ---------------- CSR bucket fill ----------------
__global__ void fill_kernel(const int* __restrict__ src, const int* __restrict__ dst, int E,
                            const int* __restrict__ row_start, int* __restrict__ cursor,
                            int* __restrict__ csr_src) {
    int e = blockIdx.x * blockDim.x + threadIdx.x;
    if (e < E) {
        int d = dst[e];
        int pos = row_start[d] + atomicAdd(&cursor[d], 1);
        csr_src[pos] = src[e];
    }
}

// ---------------- W -> transposed single bf16 ----------------
__global__ void wprep_kernel(const float* __restrict__ W, unsigned short* __restrict__ Wt) {
    int k = blockIdx.x;
    int n = threadIdx.x;
    Wt[n * DIM + k] = f32_to_bf16(W[k * DIM + n]);
}

// ---------------- x0 -> bf16 (layer-0 gather source AND residual source) ----------------
__global__ void xprep_kernel(const float* __restrict__ x, unsigned short* __restrict__ act,
                             unsigned short* __restrict__ x0b, int n4) {
    int i = blockIdx.x * blockDim.x + threadIdx.x;
    if (i < n4) {
        float4 v = ((const float4*)x)[i];
        ushort4 o;
        o.x = f32_to_bf16(v.x); o.y = f32_to_bf16(v.y);
        o.z = f32_to_bf16(v.z); o.w = f32_to_bf16(v.w);
        ((ushort4*)act)[i] = o;
        ((ushort4*)x0b)[i] = o;
    }
}

// ---------------- gather aggregation (bf16 src) + residual mix -> bf16 h ----------------
// one 64-lane wave per node; lane owns 4 contiguous columns (8B loads); edge loop x4 ILP.
__global__ __launch_bounds__(256) void aggregate_kernel(
    const unsigned short* __restrict__ xh, const unsigned short* __restrict__ x0b,
    const int* __restrict__ row_start, const int* __restrict__ csr_src,
    const float* __restrict__ inv_deg,
    unsigned short* __restrict__ h, int N)
{
    int node = blockIdx.x * 4 + (threadIdx.x >> 6);
    if (node >= N) return;
    int c = (threadIdx.x & 63) * 4;

    int beg = row_start[node];
    int end = row_start[node + 1];

    float a0 = 0.f, a1 = 0.f, a2 = 0.f, a3 = 0.f;
    int e = beg;
    for (; e + 4 <= end; e += 4) {
        int s0 = csr_src[e];
        int s1 = csr_src[e + 1];
        int s2 = csr_src[e + 2];
        int s3 = csr_src[e + 3];
        ushort4 v0 = *(const ushort4*)(xh + (size_t)s0 * DIM + c);
        ushort4 v1 = *(const ushort4*)(xh + (size_t)s1 * DIM + c);
        ushort4 v2 = *(const ushort4*)(xh + (size_t)s2 * DIM + c);
        ushort4 v3 = *(const ushort4*)(xh + (size_t)s3 * DIM + c);
        a0 += (bf16_to_f32(v0.x) + bf16_to_f32(v1.x)) + (bf16_to_f32(v2.x) + bf16_to_f32(v3.x));
        a1 += (bf16_to_f32(v0.y) + bf16_to_f32(v1.y)) + (bf16_to_f32(v2.y) + bf16_to_f32(v3.y));
        a2 += (bf16_to_f32(v0.z) + bf16_to_f32(v1.z)) + (bf16_to_f32(v2.z) + bf16_to_f32(v3.z));
        a3 += (bf16_to_f32(v0.w) + bf16_to_f32(v1.w)) + (bf16_to_f32(v2.w) + bf16_to_f32(v3.w));
    }
    for (; e < end; e++) {
        int s0 = csr_src[e];
        ushort4 v0 = *(const ushort4*)(xh + (size_t)s0 * DIM + c);
        a0 += bf16_to_f32(v0.x);
        a1 += bf16_to_f32(v0.y);
        a2 += bf16_to_f32(v0.z);
        a3 += bf16_to_f32(v0.w);
    }

    float scale = 0.9f * inv_deg[node];
    ushort4 xv = *(const ushort4*)(x0b + (size_t)node * DIM + c);
    ushort4 o;
    o.x = f32_to_bf16(0.1f * bf16_to_f32(xv.x) + scale * a0);
    o.y = f32_to_bf16(0.1f * bf16_to_f32(xv.y) + scale * a1);
    o.z = f32_to_bf16(0.1f * bf16_to_f32(xv.z) + scale * a2);
    o.w = f32_to_bf16(0.1f * bf16_to_f32(xv.w) + scale * a3);
    *(ushort4*)(h + (size_t)node * DIM + c) = o;
}

// ---------------- LDS-staged MFMA GEMM: out = relu(h @ W), pure bf16 ----------------
// 128x128 tile per 256-thread block; 4 waves 2x2; each wave 4x4 frags of 16x16x32.
template <bool LAST>
__global__ __launch_bounds__(256) void gemm_kernel(
    const unsigned short* __restrict__ h, const unsigned short* __restrict__ Wt,
    float* __restrict__ out_f32, unsigned short* __restrict__ out_bf16, int N)
{
    __shared__ unsigned short As[128 * 32];  // 8 KB
    __shared__ unsigned short Bs[128 * 32];  // 8 KB

    const int t    = threadIdx.x;
    const int w    = t >> 6;
    const int lane = t & 63;
    const int lm   = lane & 15;
    const int q    = lane >> 4;
    const int wm   = w >> 1, wn = w & 1;
    const int m0   = blockIdx.x * 128;
    const int n0   = blockIdx.y * 128;

    const int sr = t >> 2;       // 0..63
    const int sg = (t & 3) * 8;  // 16B granule

    f32x4 acc[4][4];
    #pragma unroll
    for (int mi = 0; mi < 4; mi++)
        #pragma unroll
        for (int ni = 0; ni < 4; ni++)
            acc[mi][ni] = (f32x4){0.f, 0.f, 0.f, 0.f};

    for (int kb = 0; kb < DIM; kb += 32) {
        __syncthreads();
        #pragma unroll
        for (int half = 0; half < 2; half++) {
            int r = half * 64 + sr;
            int ldso = (half * 256 + t) * 8;
            load_lds16(h  + (size_t)(m0 + r) * DIM + kb + sg, &As[ldso]);
            load_lds16(Wt + (size_t)(n0 + r) * DIM + kb + sg, &Bs[ldso]);
        }
        __syncthreads();

        short8 a[4];
        #pragma unroll
        for (int mi = 0; mi < 4; mi++) {
            int row = wm * 64 + mi * 16 + lm;
            a[mi] = *(const short8*)&As[row * 32 + q * 8];
        }
        #pragma unroll
        for (int ni = 0; ni < 4; ni++) {
            int row = wn * 64 + ni * 16 + lm;
            short8 b = *(const short8*)&Bs[row * 32 + q * 8];
            #pragma unroll
            for (int mi = 0; mi < 4; mi++)
                acc[mi][ni] = __builtin_amdgcn_mfma_f32_16x16x32_bf16(a[mi], b, acc[mi][ni], 0, 0, 0);
        }
    }

    // epilogue: C/D layout col=lane&15, row=q*4+reg (verified R4)
    #pragma unroll
    for (int mi = 0; mi < 4; mi++) {
        const int rowb = m0 + wm * 64 + mi * 16 + q * 4;
        #pragma unroll
        for (int ni = 0; ni < 4; ni++) {
            const int col = n0 + wn * 64 + ni * 16 + lm;
            #pragma unroll
            for (int r = 0; r < 4; r++) {
                int row = rowb + r;
                if (row < N) {
                    float v = fmaxf(acc[mi][ni][r], 0.0f);
                    if (LAST) out_f32[(size_t)row * DIM + col] = v;
                    else      out_bf16[(size_t)row * DIM + col] = f32_to_bf16(v);
                }
            }
        }
    }
}

extern "C" void kernel_launch(void* const* d_in, const int* in_sizes, int n_in,
                              void* d_out, int out_size, void* d_ws, size_t ws_size,
                              hipStream_t stream) {
    const float* x0  = (const float*)d_in[0];
    const int*   ei  = (const int*)d_in[1];
    const float* W   = (const float*)d_in[2];
    float*       out = (float*)d_out;

    const int N = in_sizes[0] / DIM;
    const int E = in_sizes[1] / 2;
    const int N_pad = (N + 127) & ~127;
    const int* src = ei;
    const int* dst = ei + E;

    const int nb = (N + 1 + SCAN_B - 1) / SCAN_B;

    char* ws = (char*)d_ws;
    size_t off = 0;
    auto alloc = [&](size_t bytes) { char* p = ws + off; off += (bytes + 15) & ~size_t(15); return p; };
    unsigned short* h       = (unsigned short*)alloc((size_t)N_pad * DIM * 2);
    unsigned short* act     = (unsigned short*)alloc((size_t)N_pad * DIM * 2);
    unsigned short* x0b     = (unsigned short*)alloc((size_t)N_pad * DIM * 2);
    unsigned short* Wt      = (unsigned short*)alloc((size_t)DIM * DIM * 2);
    float* inv_deg  = (float*)alloc((size_t)N * 4);
    int*   deg      = (int*)  alloc((size_t)N * 4);
    int*   row_start= (int*)  alloc((size_t)(N + 1) * 4);
    int*   excl     = (int*)  alloc((size_t)(N + 1) * 4);
    int*   cursor   = (int*)  alloc((size_t)N * 4);
    int*   bsums    = (int*)  alloc((size_t)nb * 4);
    int*   csr_src  = (int*)  alloc((size_t)E * 4);

    // ---- CSR build + W/x0 prep (per launch) ----
    hipMemsetAsync(deg, 0, (size_t)N * 4, stream);
    hipMemsetAsync(cursor, 0, (size_t)N * 4, stream);
    deg_kernel<<<(E + 255) / 256, 256, 0, stream>>>(dst, E, deg);
    scan1_kernel<<<nb, SCAN_B, 0, stream>>>(deg, N, excl, bsums);
    scan2_kernel<<<1, SCAN_B, 0, stream>>>(bsums, nb);
    scan3_kernel<<<nb, SCAN_B, 0, stream>>>(excl, bsums, deg, N, row_start, inv_deg);
    fill_kernel<<<(E + 255) / 256, 256, 0, stream>>>(src, dst, E, row_start, cursor, csr_src);
    wprep_kernel<<<DIM, DIM, 0, stream>>>(W, Wt);
    const int n4 = N * DIM / 4;
    xprep_kernel<<<(n4 + 255) / 256, 256, 0, stream>>>(x0, act, x0b, n4);

    // ---- 5 GCN layers ----
    dim3 ggrid(N_pad / 128, 2);
    for (int layer = 0; layer < 5; layer++) {
        aggregate_kernel<<<(N + 3) / 4, 256, 0, stream>>>(act, x0b, row_start, csr_src,
                                                          inv_deg, h, N);
        if (layer == 4)
            gemm_kernel<true><<<ggrid, 256, 0, stream>>>(h, Wt, out, nullptr, N);
        else
            gemm_kernel<false><<<ggrid, 256, 0, stream>>>(h, Wt, nullptr, act, N);
    }
}

// Round 10
// 384.348 us; speedup vs baseline: 1.9901x; 1.0302x over previous
//
#include <hip/hip_runtime.h>

#define DIM 256
#define SCAN_B 256

typedef __attribute__((ext_vector_type(8))) short short8;
typedef __attribute__((ext_vector_type(8))) unsigned short u16x8;
typedef __attribute__((ext_vector_type(4))) float f32x4;

__device__ __forceinline__ unsigned short f32_to_bf16(float x) {
    unsigned int u = __float_as_uint(x);
    unsigned int r = u + 0x7FFFu + ((u >> 16) & 1u);
    return (unsigned short)(r >> 16);
}
__device__ __forceinline__ float bf16_to_f32(unsigned short h) {
    return __uint_as_float(((unsigned int)h) << 16);
}

__device__ __forceinline__ void load_lds16(const void* g, void* l) {
    __builtin_amdgcn_global_load_lds(
        (const __attribute__((address_space(1))) unsigned int*)g,
        (__attribute__((address_space(3))) unsigned int*)l, 16, 0, 0);
}

// ---------------- degree histogram ----------------
__global__ void deg_kernel(const int* __restrict__ dst, int E, int* __restrict__ deg) {
    int e = blockIdx.x * blockDim.x + threadIdx.x;
    if (e < E) atomicAdd(&deg[dst[e]], 1);
}

// ---------------- hierarchical exclusive scan (deg -> row_start) ----------------
__global__ void scan1_kernel(const int* __restrict__ deg, int N,
                             int* __restrict__ excl, int* __restrict__ bsums) {
    __shared__ int s[SCAN_B];
    int tid = threadIdx.x;
    int i = blockIdx.x * SCAN_B + tid;
    int v = (i < N) ? deg[i] : 0;
    s[tid] = v;
    __syncthreads();
    #pragma unroll
    for (int off = 1; off < SCAN_B; off <<= 1) {
        int t = (tid >= off) ? s[tid - off] : 0;
        __syncthreads();
        s[tid] += t;
        __syncthreads();
    }
    if (i <= N) excl[i] = s[tid] - v;
    if (tid == SCAN_B - 1) bsums[blockIdx.x] = s[tid];
}

__global__ void scan2_kernel(int* __restrict__ bsums, int nb) {
    __shared__ int s[SCAN_B];
    int tid = threadIdx.x;
    int v = (tid < nb) ? bsums[tid] : 0;
    s[tid] = v;
    __syncthreads();
    #pragma unroll
    for (int off = 1; off < SCAN_B; off <<= 1) {
        int t = (tid >= off) ? s[tid - off] : 0;
        __syncthreads();
        s[tid] += t;
        __syncthreads();
    }
    if (tid < nb) bsums[tid] = s[tid] - v;
}

// scan3 + inv_deg fused
__global__ void scan3_kernel(const int* __restrict__ excl, const int* __restrict__ bsums,
                             const int* __restrict__ deg, int N,
                             int* __restrict__ row_start, float* __restrict__ inv_deg) {
    int i = blockIdx.x * SCAN_B + threadIdx.x;
    if (i <= N) row_start[i] = excl[i] + bsums[blockIdx.x];
    if (i < N) inv_deg[i] = 1.0f / (float)max(deg[i], 1);
}

// ---------------- CSR bucket fill ----------------
__global__ void fill_kernel(const int* __restrict__ src, const int* __restrict__ dst, int E,
                            const int* __restrict__ row_start, int* __restrict__ cursor,
                            int* __restrict__ csr_src) {
    int e = blockIdx.x * blockDim.x + threadIdx.x;
    if (e < E) {
        int d = dst[e];
        int pos = row_start[d] + atomicAdd(&cursor[d], 1);
        csr_src[pos] = src[e];
    }
}

// ---------------- combined prep: W -> bf16 transpose, x0 -> bf16 ----------------
// blocks [0, DIM): wprep (block = k row of W); blocks [DIM, ...): x0 cast
__global__ void prep_kernel(const float* __restrict__ W, unsigned short* __restrict__ Wt,
                            const float* __restrict__ x0, unsigned short* __restrict__ x0b,
                            int n4) {
    int b = blockIdx.x;
    if (b < DIM) {
        int k = b, n = threadIdx.x;
        Wt[n * DIM + k] = f32_to_bf16(W[k * DIM + n]);
    } else {
        int i = (b - DIM) * 256 + threadIdx.x;
        if (i < n4) {
            float4 v = ((const float4*)x0)[i];
            ushort4 o;
            o.x = f32_to_bf16(v.x); o.y = f32_to_bf16(v.y);
            o.z = f32_to_bf16(v.z); o.w = f32_to_bf16(v.w);
            ((ushort4*)x0b)[i] = o;
        }
    }
}

// ---------------- gather aggregation (bf16 src, 16B/lane) + residual mix -> bf16 h ----
// one 64-lane wave per node; lane owns 8 columns; the two wave halves process two
// edges concurrently (2 x 512B segments per load instruction); __shfl_xor combines.
__global__ __launch_bounds__(256) void aggregate_kernel(
    const unsigned short* __restrict__ xh, const unsigned short* __restrict__ x0b,
    const int* __restrict__ row_start, const int* __restrict__ csr_src,
    const float* __restrict__ inv_deg,
    unsigned short* __restrict__ h, int N)
{
    int node = blockIdx.x * 4 + (threadIdx.x >> 6);
    if (node >= N) return;
    const int lane = threadIdx.x & 63;
    const int half = lane >> 5;
    const int c    = (lane & 31) * 8;   // 8-column base

    int beg = row_start[node];
    int end = row_start[node + 1];

    float a[8];
    #pragma unroll
    for (int j = 0; j < 8; j++) a[j] = 0.f;

    int e = beg;
    for (; e + 4 <= end; e += 4) {           // 4 edges per iter (2 per half)
        int s0 = csr_src[e + half];
        int s1 = csr_src[e + 2 + half];
        u16x8 v0 = *(const u16x8*)(xh + (size_t)s0 * DIM + c);
        u16x8 v1 = *(const u16x8*)(xh + (size_t)s1 * DIM + c);
        #pragma unroll
        for (int j = 0; j < 8; j++) a[j] += bf16_to_f32(v0[j]) + bf16_to_f32(v1[j]);
    }
    if (e + 2 <= end) {                      // 2-edge remainder
        int s0 = csr_src[e + half];
        u16x8 v0 = *(const u16x8*)(xh + (size_t)s0 * DIM + c);
        #pragma unroll
        for (int j = 0; j < 8; j++) a[j] += bf16_to_f32(v0[j]);
        e += 2;
    }
    if (e < end && half == 0) {              // odd tail: lo half only
        int s0 = csr_src[e];
        u16x8 v0 = *(const u16x8*)(xh + (size_t)s0 * DIM + c);
        #pragma unroll
        for (int j = 0; j < 8; j++) a[j] += bf16_to_f32(v0[j]);
    }

    // combine halves (all lanes participate)
    #pragma unroll
    for (int j = 0; j < 8; j++) a[j] += __shfl_xor(a[j], 32);

    if (half == 0) {
        float scale = 0.9f * inv_deg[node];
        u16x8 xv = *(const u16x8*)(x0b + (size_t)node * DIM + c);
        u16x8 o;
        #pragma unroll
        for (int j = 0; j < 8; j++)
            o[j] = f32_to_bf16(0.1f * bf16_to_f32(xv[j]) + scale * a[j]);
        *(u16x8*)(h + (size_t)node * DIM + c) = o;
    }
}

// ---------------- LDS-staged MFMA GEMM: out = relu(h @ W), pure bf16 (R9-verified) ----
template <bool LAST>
__global__ __launch_bounds__(256) void gemm_kernel(
    const unsigned short* __restrict__ h, const unsigned short* __restrict__ Wt,
    float* __restrict__ out_f32, unsigned short* __restrict__ out_bf16, int N)
{
    __shared__ unsigned short As[128 * 32];  // 8 KB
    __shared__ unsigned short Bs[128 * 32];  // 8 KB

    const int t    = threadIdx.x;
    const int w    = t >> 6;
    const int lane = t & 63;
    const int lm   = lane & 15;
    const int q    = lane >> 4;
    const int wm   = w >> 1, wn = w & 1;
    const int m0   = blockIdx.x * 128;
    const int n0   = blockIdx.y * 128;

    const int sr = t >> 2;
    const int sg = (t & 3) * 8;

    f32x4 acc[4][4];
    #pragma unroll
    for (int mi = 0; mi < 4; mi++)
        #pragma unroll
        for (int ni = 0; ni < 4; ni++)
            acc[mi][ni] = (f32x4){0.f, 0.f, 0.f, 0.f};

    for (int kb = 0; kb < DIM; kb += 32) {
        __syncthreads();
        #pragma unroll
        for (int half = 0; half < 2; half++) {
            int r = half * 64 + sr;
            int ldso = (half * 256 + t) * 8;
            load_lds16(h  + (size_t)(m0 + r) * DIM + kb + sg, &As[ldso]);
            load_lds16(Wt + (size_t)(n0 + r) * DIM + kb + sg, &Bs[ldso]);
        }
        __syncthreads();

        short8 a[4];
        #pragma unroll
        for (int mi = 0; mi < 4; mi++) {
            int row = wm * 64 + mi * 16 + lm;
            a[mi] = *(const short8*)&As[row * 32 + q * 8];
        }
        #pragma unroll
        for (int ni = 0; ni < 4; ni++) {
            int row = wn * 64 + ni * 16 + lm;
            short8 b = *(const short8*)&Bs[row * 32 + q * 8];
            #pragma unroll
            for (int mi = 0; mi < 4; mi++)
                acc[mi][ni] = __builtin_amdgcn_mfma_f32_16x16x32_bf16(a[mi], b, acc[mi][ni], 0, 0, 0);
        }
    }

    #pragma unroll
    for (int mi = 0; mi < 4; mi++) {
        const int rowb = m0 + wm * 64 + mi * 16 + q * 4;
        #pragma unroll
        for (int ni = 0; ni < 4; ni++) {
            const int col = n0 + wn * 64 + ni * 16 + lm;
            #pragma unroll
            for (int r = 0; r < 4; r++) {
                int row = rowb + r;
                if (row < N) {
                    float v = fmaxf(acc[mi][ni][r], 0.0f);
                    if (LAST) out_f32[(size_t)row * DIM + col] = v;
                    else      out_bf16[(size_t)row * DIM + col] = f32_to_bf16(v);
                }
            }
        }
    }
}

extern "C" void kernel_launch(void* const* d_in, const int* in_sizes, int n_in,
                              void* d_out, int out_size, void* d_ws, size_t ws_size,
                              hipStream_t stream) {
    const float* x0  = (const float*)d_in[0];
    const int*   ei  = (const int*)d_in[1];
    const float* W   = (const float*)d_in[2];
    float*       out = (float*)d_out;

    const int N = in_sizes[0] / DIM;
    const int E = in_sizes[1] / 2;
    const int N_pad = (N + 127) & ~127;
    const int* src = ei;
    const int* dst = ei + E;

    const int nb = (N + 1 + SCAN_B - 1) / SCAN_B;

    char* ws = (char*)d_ws;
    size_t off = 0;
    auto alloc = [&](size_t bytes) { char* p = ws + off; off += (bytes + 15) & ~size_t(15); return p; };
    unsigned short* h       = (unsigned short*)alloc((size_t)N_pad * DIM * 2);
    unsigned short* act     = (unsigned short*)alloc((size_t)N_pad * DIM * 2);
    unsigned short* x0b     = (unsigned short*)alloc((size_t)N_pad * DIM * 2);
    unsigned short* Wt      = (unsigned short*)alloc((size_t)DIM * DIM * 2);
    float* inv_deg  = (float*)alloc((size_t)N * 4);
    int*   deg      = (int*)  alloc((size_t)N * 4 * 2);   // deg + cursor, adjacent
    int*   cursor   = deg + N;
    int*   row_start= (int*)  alloc((size_t)(N + 1) * 4);
    int*   excl     = (int*)  alloc((size_t)(N + 1) * 4);
    int*   bsums    = (int*)  alloc((size_t)nb * 4);
    int*   csr_src  = (int*)  alloc((size_t)E * 4);

    // ---- CSR build + W/x0 prep (per launch) ----
    hipMemsetAsync(deg, 0, (size_t)N * 4 * 2, stream);   // deg + cursor in one shot
    deg_kernel<<<(E + 255) / 256, 256, 0, stream>>>(dst, E, deg);
    scan1_kernel<<<nb, SCAN_B, 0, stream>>>(deg, N, excl, bsums);
    scan2_kernel<<<1, SCAN_B, 0, stream>>>(bsums, nb);
    scan3_kernel<<<nb, SCAN_B, 0, stream>>>(excl, bsums, deg, N, row_start, inv_deg);
    fill_kernel<<<(E + 255) / 256, 256, 0, stream>>>(src, dst, E, row_start, cursor, csr_src);
    const int n4 = N * DIM / 4;
    prep_kernel<<<DIM + (n4 + 255) / 256, 256, 0, stream>>>(W, Wt, x0, x0b, n4);

    // ---- 5 GCN layers (layer 0 gathers from x0b; then act) ----
    dim3 ggrid(N_pad / 128, 2);
    for (int layer = 0; layer < 5; layer++) {
        const unsigned short* gsrc = (layer == 0) ? x0b : act;
        aggregate_kernel<<<(N + 3) / 4, 256, 0, stream>>>(gsrc, x0b, row_start, csr_src,
                                                          inv_deg, h, N);
        if (layer == 4)
            gemm_kernel<true><<<ggrid, 256, 0, stream>>>(h, Wt, out, nullptr, N);
        else
            gemm_kernel<false><<<ggrid, 256, 0, stream>>>(h, Wt, nullptr, act, N);
    }
}